// Round 10
// baseline (6482.009 us; speedup 1.0000x reference)
//
#include <hip/hip_runtime.h>
#include <hip/hip_bf16.h>
#include <math.h>

// FourierAttention  B=2 S=2048 D=1024 H=16 DK=64  SCALE=8
// Round 10 (= round 8 resubmitted; two broker timeouts, never ran).
// OUTPUTS ARE FLOAT32 (reference returns jnp.float32; harness reads f32).
// f64 score chain (proj accum, FFT, score dot, softmax max).
//   combined[q,k] = dot( [tw/8*Q | fw/8*QfR | fw/8*QfI](q) , [K | KfR | KfI](k) )
// d_out f32 = [out (4,194,304) | attn (134,217,728)].
// Scratch (Qt/Kt/Mpart/Zpart) aliased into attn region, dead before pass2 writes attn.

static __device__ __forceinline__ unsigned short f2bf_bits(float x){
  union { float f; unsigned u; } c; c.f = x;
  unsigned u = c.u;
  u += 0x7fffu + ((u >> 16) & 1u);            // RNE
  return (unsigned short)(u >> 16);
}
static __device__ __forceinline__ float bf2f(unsigned short u){
  return __uint_as_float(((unsigned)u) << 16);
}

// ---------------- projections, f64 accumulation: z=0 Q, z=1 K, z=2 V ----------------
__global__ void __launch_bounds__(256) k_proj64(
    const float* __restrict__ x,
    const float* __restrict__ Wq, const float* __restrict__ Wk, const float* __restrict__ Wv,
    const float* __restrict__ bq, const float* __restrict__ bk, const float* __restrict__ bv,
    const float* __restrict__ twp,
    float* __restrict__ QcatT, float* __restrict__ KcatT,
    float* __restrict__ Qt, float* __restrict__ Kt,
    unsigned short* __restrict__ Vn)
{
  __shared__ float xt[64][33];
  __shared__ float wt[64][33];
  const int nt = blockIdx.x, mt = blockIdx.y, z = blockIdx.z;
  const int m0 = mt*64, n0 = nt*64;
  const float* W = (z==0) ? Wq : (z==1) ? Wk : Wv;
  const float* bias = (z==0) ? bq : (z==1) ? bk : bv;
  const int tid = threadIdx.x, tm = tid >> 4, tn = tid & 15;

  double acc[4][4];
  #pragma unroll
  for (int i=0;i<4;++i){ acc[i][0]=0.0; acc[i][1]=0.0; acc[i][2]=0.0; acc[i][3]=0.0; }

  for (int kb = 0; kb < 32; ++kb){
    for (int cid = tid; cid < 512; cid += 256){
      const int r = cid >> 3, c4 = cid & 7;
      const float4 xv = *reinterpret_cast<const float4*>(x + (size_t)(m0+r)*1024 + kb*32 + c4*4);
      xt[r][c4*4+0]=xv.x; xt[r][c4*4+1]=xv.y; xt[r][c4*4+2]=xv.z; xt[r][c4*4+3]=xv.w;
      const float4 wv = *reinterpret_cast<const float4*>(W + (size_t)(n0+r)*1024 + kb*32 + c4*4);
      wt[r][c4*4+0]=wv.x; wt[r][c4*4+1]=wv.y; wt[r][c4*4+2]=wv.z; wt[r][c4*4+3]=wv.w;
    }
    __syncthreads();
    #pragma unroll 2
    for (int kk = 0; kk < 32; ++kk){
      double av[4], wv[4];
      #pragma unroll
      for (int i=0;i<4;++i) av[i] = (double)xt[tm*4+i][kk];
      #pragma unroll
      for (int j=0;j<4;++j) wv[j] = (double)wt[tn*4+j][kk];
      #pragma unroll
      for (int i=0;i<4;++i)
        #pragma unroll
        for (int j=0;j<4;++j) acc[i][j] = fma(av[i], wv[j], acc[i][j]);
    }
    __syncthreads();
  }

  const double tsc = (double)twp[0] * 0.125;
  #pragma unroll
  for (int i=0;i<4;++i)
    #pragma unroll
    for (int j=0;j<4;++j){
      const int m = m0 + tm*4 + i;      // b*2048 + s
      const int n = n0 + tn*4 + j;      // h*64 + d
      const double v = acc[i][j] + (double)bias[n];
      const int b_i = m >> 11, s_i = m & 2047;
      const int h_i = n >> 6,  d_i = n & 63;
      const int bh = b_i*16 + h_i;
      if (z == 0){
        QcatT[((size_t)bh*2048 + s_i)*64 + d_i] = (float)(v * tsc);
        Qt[((size_t)bh*64 + d_i)*2048 + s_i] = (float)v;
      } else if (z == 1){
        KcatT[((size_t)bh*2048 + s_i)*64 + d_i] = (float)v;
        Kt[((size_t)bh*64 + d_i)*2048 + s_i] = (float)v;
      } else {
        Vn[((size_t)bh*2048 + s_i)*64 + d_i] = f2bf_bits((float)v);
      }
    }
}

// ------------- f64 radix-2 DIT FFT (in-place, LDS), one (bh,d) column per block -------------
__global__ void __launch_bounds__(256) k_fft64(
    const float* __restrict__ Qt, const float* __restrict__ Kt,
    double* __restrict__ QfH, double* __restrict__ KfH,
    const float* __restrict__ fwp)
{
  __shared__ double2 buf[2048];   // 32 KB
  __shared__ double2 twd[1024];   // 16 KB
  const int d = blockIdx.x, bh = blockIdx.y, z = blockIdx.z;
  const float* in = (z ? Kt : Qt) + ((size_t)bh*64 + d)*2048;
  double* out = (z ? KfH : QfH) + (size_t)bh*1025*128;
  const double fsc = z ? 1.0 : ((double)fwp[0] * 0.125);
  const int tid = threadIdx.x;

  for (int j = tid; j < 1024; j += 256){
    const double a = -(M_PI/1024.0) * (double)j;   // -2*pi*j/2048
    twd[j].x = cos(a); twd[j].y = sin(a);
  }
  for (int i = tid; i < 2048; i += 256){
    const int br = __brev((unsigned)i) >> 21;      // 11-bit reverse
    buf[i].x = (double)in[br]; buf[i].y = 0.0;
  }
  __syncthreads();

  #pragma unroll 1
  for (int ls = 1; ls <= 11; ++ls){
    const int half = 1 << (ls-1);
    const int tsh  = 11 - ls;
    for (int t = tid; t < 1024; t += 256){
      const int j  = t & (half-1);
      const int i0 = ((t >> (ls-1)) << ls) + j;
      const int i1 = i0 + half;
      const double2 w = twd[j << tsh];
      const double2 b = buf[i1];
      const double bwx = b.x*w.x - b.y*w.y;
      const double bwy = b.x*w.y + b.y*w.x;
      const double2 a = buf[i0];
      buf[i0].x = a.x + bwx; buf[i0].y = a.y + bwy;
      buf[i1].x = a.x - bwx; buf[i1].y = a.y - bwy;
    }
    __syncthreads();
  }

  for (int s = tid; s < 1025; s += 256){
    out[(size_t)s*128 + d]      = buf[s].x * fsc;
    out[(size_t)s*128 + 64 + d] = buf[s].y * fsc;
  }
}

// ---------------- scores, f64 accumulate; PASS1 stats, PASS2 f32 attn ----------------
template<int PASS>
__global__ void __launch_bounds__(256) k_score64(
    const float* __restrict__ QcatT, const float* __restrict__ KcatT,
    const double* __restrict__ QfH, const double* __restrict__ KfH,
    double* __restrict__ Mpart, float* __restrict__ Zpart,
    const double* __restrict__ Mrow, const float* __restrict__ Zinv,
    float* __restrict__ attn)
{
  __shared__ double At[64][33];
  __shared__ double Bt[64][33];
  const int kt = blockIdx.x, qt = blockIdx.y, bh = blockIdx.z;
  const int tid = threadIdx.x, tq = tid >> 4, tk = tid & 15;

  double acc[4][4];
  #pragma unroll
  for (int i=0;i<4;++i){ acc[i][0]=0.0; acc[i][1]=0.0; acc[i][2]=0.0; acc[i][3]=0.0; }

  // ---- time chunks (f32 operands, 2 x 32) ----
  for (int tc = 0; tc < 2; ++tc){
    const int c0 = tc*32;
    for (int cid = tid; cid < 2048; cid += 256){
      const int r = cid >> 5, c = cid & 31;
      At[r][c] = (double)QcatT[((size_t)bh*2048 + qt*64 + r)*64 + c0 + c];
      Bt[r][c] = (double)KcatT[((size_t)bh*2048 + kt*64 + r)*64 + c0 + c];
    }
    __syncthreads();
    #pragma unroll 2
    for (int kk = 0; kk < 32; ++kk){
      double qv[4], kv[4];
      #pragma unroll
      for (int i=0;i<4;++i) qv[i] = At[tq*4+i][kk];
      #pragma unroll
      for (int j=0;j<4;++j) kv[j] = Bt[tk*4+j][kk];
      #pragma unroll
      for (int i=0;i<4;++i)
        #pragma unroll
        for (int j=0;j<4;++j) acc[i][j] = fma(qv[i], kv[j], acc[i][j]);
    }
    __syncthreads();
  }

  // ---- freq chunks (f64 half-spectrum; cols>=64 are Im; Hermitian mirror) ----
  for (int fc = 0; fc < 4; ++fc){
    for (int cid = tid; cid < 2048; cid += 256){
      const int r = cid >> 5, c = cid & 31;
      {
        const int sg = qt*64 + r;
        const int mir = sg > 1024;
        const size_t srow = mir ? (2048 - sg) : sg;
        const double sign = (mir && fc >= 2) ? -1.0 : 1.0;     // true Im(Qf[sg])
        At[r][c] = sign * QfH[((size_t)bh*1025 + srow)*128 + fc*32 + c];
      }
      {
        const int sg = kt*64 + r;
        const int mir = sg > 1024;
        const size_t srow = mir ? (2048 - sg) : sg;
        const double sign = (mir && fc >= 2) ? -1.0 : 1.0;     // true Im(Kf[sg])
        Bt[r][c] = sign * KfH[((size_t)bh*1025 + srow)*128 + fc*32 + c];
      }
    }
    __syncthreads();
    #pragma unroll 2
    for (int kk = 0; kk < 32; ++kk){
      double qv[4], kv[4];
      #pragma unroll
      for (int i=0;i<4;++i) qv[i] = At[tq*4+i][kk];
      #pragma unroll
      for (int j=0;j<4;++j) kv[j] = Bt[tk*4+j][kk];
      #pragma unroll
      for (int i=0;i<4;++i)
        #pragma unroll
        for (int j=0;j<4;++j) acc[i][j] = fma(qv[i], kv[j], acc[i][j]);
    }
    __syncthreads();
  }

  if (PASS == 1){
    #pragma unroll
    for (int i=0;i<4;++i){
      double m = acc[i][0];
      #pragma unroll
      for (int j=1;j<4;++j) m = fmax(m, acc[i][j]);
      #pragma unroll
      for (int dd=1; dd<16; dd<<=1) m = fmax(m, __shfl_xor(m, dd));
      float zz = 0.f;
      #pragma unroll
      for (int j=0;j<4;++j) zz += __expf((float)(acc[i][j] - m));
      #pragma unroll
      for (int dd=1; dd<16; dd<<=1) zz += __shfl_xor(zz, dd);
      if (tk == 0){
        const size_t gq = (size_t)bh*2048 + qt*64 + tq*4 + i;
        Mpart[gq*32 + kt] = m;
        Zpart[gq*32 + kt] = zz;
      }
    }
  } else {
    #pragma unroll
    for (int i=0;i<4;++i){
      const size_t gq = (size_t)bh*2048 + qt*64 + tq*4 + i;
      const double M = Mrow[gq];
      const float Zi = Zinv[gq];
      float4 pk;
      pk.x = __expf((float)(acc[i][0] - M)) * Zi;
      pk.y = __expf((float)(acc[i][1] - M)) * Zi;
      pk.z = __expf((float)(acc[i][2] - M)) * Zi;
      pk.w = __expf((float)(acc[i][3] - M)) * Zi;
      *reinterpret_cast<float4*>(attn + gq*2048 + kt*64 + tk*4) = pk;
    }
  }
}

__global__ void __launch_bounds__(256) k_reduce64(const double* __restrict__ Mpart,
    const float* __restrict__ Zpart, double* __restrict__ Mrow, float* __restrict__ Zinv)
{
  const int i = blockIdx.x*256 + threadIdx.x;   // 65536 rows
  double M = -1.0e300;
  #pragma unroll
  for (int t = 0; t < 32; ++t) M = fmax(M, Mpart[(size_t)i*32 + t]);
  float Z = 0.f;
  #pragma unroll
  for (int t = 0; t < 32; ++t) Z += Zpart[(size_t)i*32 + t] * __expf((float)(Mpart[(size_t)i*32 + t] - M));
  Mrow[i] = M; Zinv[i] = 1.0f / Z;
}

// ---------------- PV (fp32 VALU): out[q][d] = sum_k attn[q][k] * Vn[k][d] ----------------
__global__ void __launch_bounds__(256) k_pvv(const float* __restrict__ attn,
    const unsigned short* __restrict__ Vn, unsigned short* __restrict__ outh)
{
  __shared__ float at[128][65];
  __shared__ float vt[64][65];
  const int qt = blockIdx.x, bh = blockIdx.y;
  const int tid = threadIdx.x, tq = tid >> 4, td = tid & 15;
  const size_t arow0 = ((size_t)bh*2048 + qt*128)*2048;

  float acc[8][4];
  #pragma unroll
  for (int i=0;i<8;++i){ acc[i][0]=0.f; acc[i][1]=0.f; acc[i][2]=0.f; acc[i][3]=0.f; }

  for (int kb = 0; kb < 32; ++kb){
    for (int cid = tid; cid < 2048; cid += 256){
      const int r = cid >> 4, c4 = cid & 15;
      const float4 v = *reinterpret_cast<const float4*>(attn + arow0 + (size_t)r*2048 + kb*64 + c4*4);
      at[r][c4*4+0]=v.x; at[r][c4*4+1]=v.y; at[r][c4*4+2]=v.z; at[r][c4*4+3]=v.w;
    }
    for (int cid = tid; cid < 512; cid += 256){
      const int r = cid >> 3, c8 = cid & 7;
      union { uint4 v; unsigned short us[8]; } u;
      u.v = *reinterpret_cast<const uint4*>(Vn + ((size_t)bh*2048 + kb*64 + r)*64 + c8*8);
      #pragma unroll
      for (int t=0;t<8;++t) vt[r][c8*8+t] = bf2f(u.us[t]);
    }
    __syncthreads();
    #pragma unroll 4
    for (int kk = 0; kk < 64; ++kk){
      float qa[8], vv[4];
      #pragma unroll
      for (int i=0;i<8;++i) qa[i] = at[tq*8+i][kk];
      #pragma unroll
      for (int j=0;j<4;++j) vv[j] = vt[kk][td*4+j];
      #pragma unroll
      for (int i=0;i<8;++i)
        #pragma unroll
        for (int j=0;j<4;++j) acc[i][j] += qa[i]*vv[j];
    }
    __syncthreads();
  }
  const int b_i = bh >> 4, h_i = bh & 15;
  #pragma unroll
  for (int i=0;i<8;++i)
    #pragma unroll
    for (int j=0;j<4;++j){
      const int q = qt*128 + tq*8 + i;
      outh[((size_t)b_i*2048 + q)*1024 + h_i*64 + td*4 + j] = f2bf_bits(acc[i][j]);
    }
}

// ---------------- out projection (fp32 VALU, f32 output) ----------------
__global__ void __launch_bounds__(256) k_oprojv(const unsigned short* __restrict__ outh,
    const float* __restrict__ Wo, const float* __restrict__ bo,
    float* __restrict__ outp)
{
  __shared__ float at[64][33];
  __shared__ float wt[64][33];
  const int nt = blockIdx.x, mt = blockIdx.y;
  const int m0 = mt*64, n0 = nt*64;
  const int tid = threadIdx.x, tm = tid >> 4, tn = tid & 15;

  float acc[4][4];
  #pragma unroll
  for (int i=0;i<4;++i){ acc[i][0]=0.f; acc[i][1]=0.f; acc[i][2]=0.f; acc[i][3]=0.f; }

  for (int kb = 0; kb < 32; ++kb){
    for (int cid = tid; cid < 256; cid += 256){
      const int r = cid >> 2, c8 = cid & 3;
      union { uint4 v; unsigned short us[8]; } u;
      u.v = *reinterpret_cast<const uint4*>(outh + (size_t)(m0+r)*1024 + kb*32 + c8*8);
      #pragma unroll
      for (int t=0;t<8;++t) at[r][c8*8+t] = bf2f(u.us[t]);
    }
    for (int cid = tid; cid < 512; cid += 256){
      const int r = cid >> 3, c4 = cid & 7;
      const float4 wv = *reinterpret_cast<const float4*>(Wo + (size_t)(n0+r)*1024 + kb*32 + c4*4);
      wt[r][c4*4+0]=wv.x; wt[r][c4*4+1]=wv.y; wt[r][c4*4+2]=wv.z; wt[r][c4*4+3]=wv.w;
    }
    __syncthreads();
    #pragma unroll 4
    for (int kk = 0; kk < 32; ++kk){
      float av[4], wv[4];
      #pragma unroll
      for (int i=0;i<4;++i) av[i] = at[tm*4+i][kk];
      #pragma unroll
      for (int j=0;j<4;++j) wv[j] = wt[tn*4+j][kk];
      #pragma unroll
      for (int i=0;i<4;++i)
        #pragma unroll
        for (int j=0;j<4;++j) acc[i][j] += av[i]*wv[j];
    }
    __syncthreads();
  }
  #pragma unroll
  for (int i=0;i<4;++i)
    #pragma unroll
    for (int j=0;j<4;++j){
      const int m = m0 + tm*4 + i;
      const int n = n0 + tn*4 + j;
      outp[(size_t)m*1024 + n] = acc[i][j] + bo[n];
    }
}

extern "C" void kernel_launch(void* const* d_in, const int* in_sizes, int n_in,
                              void* d_out, int out_size, void* d_ws, size_t ws_size,
                              hipStream_t stream)
{
  (void)n_in; (void)out_size; (void)ws_size;
  const bool dictOrder = (in_sizes[0] == 4194304);

  const float *x, *Wq, *bq, *Wk, *bk, *Wv, *bv, *Wo, *bo, *twp, *fwp;
  if (dictOrder){
    x   = (const float*)d_in[0];
    Wq  = (const float*)d_in[1];  bq = (const float*)d_in[2];
    Wk  = (const float*)d_in[3];  bk = (const float*)d_in[4];
    Wv  = (const float*)d_in[5];  bv = (const float*)d_in[6];
    Wo  = (const float*)d_in[7];  bo = (const float*)d_in[8];
    twp = (const float*)d_in[9];  fwp = (const float*)d_in[10];
  } else {
    // alphabetical: Wk, Wo, Wq, Wv, bk, bo, bq, bv, freq_weight, time_weight, x
    Wk  = (const float*)d_in[0];  Wo = (const float*)d_in[1];
    Wq  = (const float*)d_in[2];  Wv = (const float*)d_in[3];
    bk  = (const float*)d_in[4];  bo = (const float*)d_in[5];
    bq  = (const float*)d_in[6];  bv = (const float*)d_in[7];
    fwp = (const float*)d_in[8];  twp = (const float*)d_in[9];
    x   = (const float*)d_in[10];
  }

  float* outp = (float*)d_out;                       // f32 [2][2048][1024]
  float* attn = outp + (size_t)4194304;              // f32 [32][2048][2048]

  // scratch aliased into the f32 attn region (dead before k_score64<2> writes attn)
  char* scr = (char*)d_out + 16777216;
  float*  Qt    = (float*) (scr + 0);            // 16,777,216
  float*  Kt    = (float*) (scr + 16777216);     // 16,777,216
  double* Mpart = (double*)(scr + 33554432);     // 16,777,216  [65536][32] f64
  float*  Zpart = (float*) (scr + 50331648);     //  8,388,608  [65536][32] f32

  // workspace: total 118,292,480 bytes
  char* wsb = (char*)d_ws;
  float*  QcatT = (float*) (wsb + 0);            // 16,777,216
  float*  KcatT = (float*) (wsb + 16777216);     // 16,777,216
  double* QfH   = (double*)(wsb + 33554432);     // 33,587,200  [32][1025][128] f64
  double* KfH   = (double*)(wsb + 67141632);     // 33,587,200
  unsigned short* Vn   = (unsigned short*)(wsb + 100728832);  // 8,388,608
  unsigned short* outh = (unsigned short*)(wsb + 109117440);  // 8,388,608
  double* Mrow  = (double*)(wsb + 117506048);    // 524,288
  float*  Zinv  = (float*) (wsb + 118030336);    // 262,144

  const dim3 T(256);
  k_proj64<<<dim3(16,64,3), T, 0, stream>>>(x, Wq, Wk, Wv, bq, bk, bv, twp,
                                            QcatT, KcatT, Qt, Kt, Vn);
  k_fft64<<<dim3(64,32,2), T, 0, stream>>>(Qt, Kt, QfH, KfH, fwp);
  k_score64<1><<<dim3(32,32,32), T, 0, stream>>>(QcatT, KcatT, QfH, KfH,
                                                 Mpart, Zpart, nullptr, nullptr, nullptr);
  k_reduce64<<<dim3(256), T, 0, stream>>>(Mpart, Zpart, Mrow, Zinv);
  k_score64<2><<<dim3(32,32,32), T, 0, stream>>>(QcatT, KcatT, QfH, KfH,
                                                 nullptr, nullptr, Mrow, Zinv, attn);
  k_pvv<<<dim3(16,32), T, 0, stream>>>(attn, Vn, outh);
  k_oprojv<<<dim3(16,64), T, 0, stream>>>(outh, Wo, bo, outp);
}